// Round 1
// baseline (330.626 us; speedup 1.0000x reference)
//
#include <hip/hip_runtime.h>
#include <hip/hip_bf16.h>

// HeteroAttLayer: h = tanh(hs @ W^T + b); att = softmax(mean_n h.meta); out = sum_c att[c]*h[c]
// C=4, N=300000, D=128. Two-pass (recompute) design: pass1 scores, softmax, pass2 output.
// ws usage: float partials[4][3125] + float att[4]  (~50 KB)

#define C_CH 4
#define N_NODES 300000
#define D_DIM 128
#define M_TILE 96
#define N_TILES (N_NODES / M_TILE)   // 3125 exactly, no tail

typedef short bf16x8 __attribute__((ext_vector_type(8)));   // 8 bf16 (4 VGPRs)
typedef float floatx4 __attribute__((ext_vector_type(4)));
typedef unsigned int uintx2 __attribute__((ext_vector_type(2)));

__device__ __forceinline__ unsigned pack_bf16_rne(float a, float b) {
    unsigned ua = __builtin_bit_cast(unsigned, a);
    unsigned ub = __builtin_bit_cast(unsigned, b);
    ua += 0x7FFFu + ((ua >> 16) & 1u);   // round-to-nearest-even
    ub += 0x7FFFu + ((ub >> 16) & 1u);
    return (ua >> 16) | (ub & 0xFFFF0000u);
}

// tanh via v_exp_f32: tanh|x| = 1 - 2/(exp(2|x|)+1); error ~1e-6 << 2e-2 threshold
__device__ __forceinline__ float fast_tanh(float x) {
    float ax = __builtin_fabsf(x);
    float e = __builtin_amdgcn_exp2f(ax * 2.8853900817779268f);  // 2*log2(e)
    float t = 1.0f - 2.0f * __builtin_amdgcn_rcpf(e + 1.0f);
    return __builtin_copysignf(t, x);
}

// Swizzled LDS byte offset for bf16 element (row, d); row stride 256 B.
// XOR of (row&7)<<4 breaks the 16-way bank conflict of stride-256B column reads
// (guide §6 G4); preserves 16B-chunk alignment so ds_read_b128/ds_write_b64 stay legal.
__device__ __forceinline__ int lds_off(int row, int d) {
    return row * 256 + ((d * 2) ^ ((row & 7) << 4));
}

// Stage ROWS x 128 fp32 -> bf16 LDS tile (swizzled). 256 threads.
template<int ROWS>
__device__ __forceinline__ void stage_bf16(const float* __restrict__ src, short* dst, int tid) {
    constexpr int NVEC = ROWS * 32;   // float4 count (multiple of 256)
    #pragma unroll
    for (int q0 = 0; q0 < NVEC; q0 += 256) {
        int q = q0 + tid;
        float4 v = reinterpret_cast<const float4*>(src)[q];
        int row = q >> 5;             // 32 float4 per row
        int d0  = (q & 31) * 4;
        uintx2 w;
        w.x = pack_bf16_rne(v.x, v.y);
        w.y = pack_bf16_rne(v.z, v.w);
        *reinterpret_cast<uintx2*>(reinterpret_cast<char*>(dst) + lds_off(row, d0)) = w;
    }
}

// Per-wave: 6 m-tiles x 2 e-tiles of 16x16, K=128 in 4 steps of 32.
// A[n][k]: lane l&15 = n-row, k = (l>>4)*8+i.  B[k][e]: lane l&15 = e-col -> B elem = W[e][k].
// D: col = lane&15, row = (lane>>4)*4 + reg   [guide §3, m89-verified]
__device__ __forceinline__ void compute_tile(const short* As, const short* Ws,
                                             int wave, int lane, floatx4 (&acc)[6][2]) {
    int l15 = lane & 15;
    int half = lane >> 4;
    #pragma unroll
    for (int s = 0; s < 4; ++s) {
        int d0 = s * 32 + half * 8;
        bf16x8 a[6], b[2];
        #pragma unroll
        for (int mt = 0; mt < 6; ++mt) {
            int row = mt * 16 + l15;
            a[mt] = *reinterpret_cast<const bf16x8*>(
                        reinterpret_cast<const char*>(As) + lds_off(row, d0));
        }
        #pragma unroll
        for (int et = 0; et < 2; ++et) {
            int row = wave * 32 + et * 16 + l15;   // e index; B[k][e] = W[e][k]
            b[et] = *reinterpret_cast<const bf16x8*>(
                        reinterpret_cast<const char*>(Ws) + lds_off(row, d0));
        }
        #pragma unroll
        for (int mt = 0; mt < 6; ++mt)
            #pragma unroll
            for (int et = 0; et < 2; ++et)
                acc[mt][et] = __builtin_amdgcn_mfma_f32_16x16x32_bf16(a[mt], b[et], acc[mt][et], 0, 0, 0);
    }
}

// Pass 1: per (tile, channel) block: z = hs_tile @ W^T; partial score = sum tanh(z+b).meta[c]
__global__ __launch_bounds__(256, 2) void score_kernel(
        const float* __restrict__ hs, const float* __restrict__ W,
        const float* __restrict__ bvec, const float* __restrict__ meta,
        float* __restrict__ partials) {
    __shared__ short As[M_TILE * D_DIM];
    __shared__ short Ws[D_DIM * D_DIM];
    __shared__ float red[4];
    int tile = blockIdx.x;
    int c = blockIdx.y;
    int tid = threadIdx.x;

    stage_bf16<128>(W, Ws, tid);
    stage_bf16<96>(hs + (size_t)c * N_NODES * D_DIM + (size_t)tile * M_TILE * D_DIM, As, tid);
    __syncthreads();

    int wave = tid >> 6, lane = tid & 63;
    floatx4 acc[6][2];
    #pragma unroll
    for (int mt = 0; mt < 6; ++mt)
        #pragma unroll
        for (int et = 0; et < 2; ++et)
            acc[mt][et] = (floatx4){0.f, 0.f, 0.f, 0.f};
    compute_tile(As, Ws, wave, lane, acc);

    int l15 = lane & 15;
    float p = 0.f;
    #pragma unroll
    for (int et = 0; et < 2; ++et) {
        int e = wave * 32 + et * 16 + l15;
        float be = bvec[e];
        float me = meta[c * D_DIM + e];
        #pragma unroll
        for (int mt = 0; mt < 6; ++mt)
            #pragma unroll
            for (int r = 0; r < 4; ++r)
                p += fast_tanh(acc[mt][et][r] + be) * me;
    }
    #pragma unroll
    for (int off = 32; off > 0; off >>= 1) p += __shfl_down(p, off);
    if (lane == 0) red[wave] = p;
    __syncthreads();
    if (tid == 0) partials[c * N_TILES + tile] = red[0] + red[1] + red[2] + red[3];
}

// Pass 2: reduce partials deterministically, softmax over 4 channels
__global__ void softmax_kernel(const float* __restrict__ partials, float* __restrict__ att_out) {
    __shared__ float red[4];
    __shared__ float totals[C_CH];
    int tid = threadIdx.x;
    int wave = tid >> 6, lane = tid & 63;
    for (int c = 0; c < C_CH; ++c) {
        float s = 0.f;
        for (int i = tid; i < N_TILES; i += 256) s += partials[c * N_TILES + i];
        #pragma unroll
        for (int off = 32; off > 0; off >>= 1) s += __shfl_down(s, off);
        if (lane == 0) red[wave] = s;
        __syncthreads();
        if (tid == 0) totals[c] = red[0] + red[1] + red[2] + red[3];
        __syncthreads();
    }
    if (tid == 0) {
        float sc[C_CH], m = -1e30f;
        #pragma unroll
        for (int c = 0; c < C_CH; ++c) {
            sc[c] = totals[c] / (float)N_NODES;
            m = fmaxf(m, sc[c]);
        }
        float sum = 0.f;
        #pragma unroll
        for (int c = 0; c < C_CH; ++c) {
            sc[c] = __builtin_amdgcn_exp2f((sc[c] - m) * 1.4426950408889634f);
            sum += sc[c];
        }
        #pragma unroll
        for (int c = 0; c < C_CH; ++c) att_out[c] = sc[c] / sum;
    }
}

// Pass 3: recompute h per channel, out = sum_c att[c]*tanh(z+b)
__global__ __launch_bounds__(256, 2) void out_kernel(
        const float* __restrict__ hs, const float* __restrict__ W,
        const float* __restrict__ bvec, const float* __restrict__ att,
        float* __restrict__ out) {
    __shared__ short As[M_TILE * D_DIM];
    __shared__ short Ws[D_DIM * D_DIM];
    int tile = blockIdx.x;
    int tid = threadIdx.x;

    stage_bf16<128>(W, Ws, tid);

    int wave = tid >> 6, lane = tid & 63;
    int l15 = lane & 15, half = lane >> 4;
    float be[2];
    #pragma unroll
    for (int et = 0; et < 2; ++et) be[et] = bvec[wave * 32 + et * 16 + l15];

    floatx4 oacc[6][2];
    #pragma unroll
    for (int mt = 0; mt < 6; ++mt)
        #pragma unroll
        for (int et = 0; et < 2; ++et)
            oacc[mt][et] = (floatx4){0.f, 0.f, 0.f, 0.f};

    for (int c = 0; c < C_CH; ++c) {
        __syncthreads();   // Ws ready (c=0) / prior compute done before As overwrite
        stage_bf16<96>(hs + (size_t)c * N_NODES * D_DIM + (size_t)tile * M_TILE * D_DIM, As, tid);
        __syncthreads();
        floatx4 acc[6][2];
        #pragma unroll
        for (int mt = 0; mt < 6; ++mt)
            #pragma unroll
            for (int et = 0; et < 2; ++et)
                acc[mt][et] = (floatx4){0.f, 0.f, 0.f, 0.f};
        compute_tile(As, Ws, wave, lane, acc);
        float ac = att[c];
        #pragma unroll
        for (int mt = 0; mt < 6; ++mt)
            #pragma unroll
            for (int et = 0; et < 2; ++et)
                #pragma unroll
                for (int r = 0; r < 4; ++r)
                    oacc[mt][et][r] += ac * fast_tanh(acc[mt][et][r] + be[et]);
    }

    #pragma unroll
    for (int mt = 0; mt < 6; ++mt)
        #pragma unroll
        for (int et = 0; et < 2; ++et)
            #pragma unroll
            for (int r = 0; r < 4; ++r) {
                int rown = tile * M_TILE + mt * 16 + half * 4 + r;
                int e = wave * 32 + et * 16 + l15;
                out[(size_t)rown * D_DIM + e] = oacc[mt][et][r];
            }
}

extern "C" void kernel_launch(void* const* d_in, const int* in_sizes, int n_in,
                              void* d_out, int out_size, void* d_ws, size_t ws_size,
                              hipStream_t stream) {
    (void)in_sizes; (void)n_in; (void)out_size; (void)ws_size;
    const float* hs   = (const float*)d_in[0];
    const float* W    = (const float*)d_in[1];
    const float* bv   = (const float*)d_in[2];
    const float* meta = (const float*)d_in[3];
    float* wsf = (float*)d_ws;
    float* partials = wsf;                    // [4][3125]
    float* att      = wsf + C_CH * N_TILES;   // [4]
    float* out      = (float*)d_out;

    score_kernel<<<dim3(N_TILES, C_CH), 256, 0, stream>>>(hs, W, bv, meta, partials);
    softmax_kernel<<<1, 256, 0, stream>>>(partials, att);
    out_kernel<<<N_TILES, 256, 0, stream>>>(hs, W, bv, att, out);
}

// Round 3
// 288.088 us; speedup vs baseline: 1.1477x; 1.1477x over previous
//
#include <hip/hip_runtime.h>
#include <hip/hip_bf16.h>

// HeteroAttLayer: h = tanh(hs @ W^T + b); att = softmax(mean_n h.meta); out = sum_c att[c]*h[c]
// C=4, N=300000, D=128. Two-pass recompute design.
// R2b: W-frags in registers (no Ws LDS), T14 reg-staged channel pipeline in out_kernel,
//      reversed tile order + nontemporal loads/stores in out pass for L3 tail reuse.
//      (fix: nontemporal builtins need clang ext_vector, not HIP float4)

#define C_CH 4
#define N_NODES 300000
#define D_DIM 128
#define M_TILE 96
#define N_TILES (N_NODES / M_TILE)   // 3125 exactly, no tail

typedef short bf16x8 __attribute__((ext_vector_type(8)));   // 8 bf16 (4 VGPRs)
typedef float floatx4 __attribute__((ext_vector_type(4)));
typedef unsigned int uintx2 __attribute__((ext_vector_type(2)));
typedef unsigned int uintx4 __attribute__((ext_vector_type(4)));

__device__ __forceinline__ unsigned pack_bf16_rne(float a, float b) {
    unsigned ua = __builtin_bit_cast(unsigned, a);
    unsigned ub = __builtin_bit_cast(unsigned, b);
    ua += 0x7FFFu + ((ua >> 16) & 1u);   // round-to-nearest-even
    ub += 0x7FFFu + ((ub >> 16) & 1u);
    return (ua >> 16) | (ub & 0xFFFF0000u);
}

// tanh via v_exp_f32: tanh|x| = 1 - 2/(exp(2|x|)+1); error ~1e-6 << 2e-2 threshold
__device__ __forceinline__ float fast_tanh(float x) {
    float ax = __builtin_fabsf(x);
    float e = __builtin_amdgcn_exp2f(ax * 2.8853900817779268f);  // 2*log2(e)
    float t = 1.0f - 2.0f * __builtin_amdgcn_rcpf(e + 1.0f);
    return __builtin_copysignf(t, x);
}

// Swizzled LDS byte offset for bf16 (row, d); row stride 256 B. XOR (row&7)<<4
// breaks the stride-256B column bank conflict (guide §6 G4), keeps 16B alignment.
__device__ __forceinline__ int lds_off(int row, int d) {
    return row * 256 + ((d * 2) ^ ((row & 7) << 4));
}

// W fragments straight into registers: bfr[et][s] = bf16 of W[e][s*32+half*8 .. +7],
// e = wave*32 + et*16 + (lane&15). 16 float4 loads + 32 packs once per block.
__device__ __forceinline__ void load_w_frags(const float* __restrict__ W,
                                             int wave, int lane, bf16x8 (&bfr)[2][4]) {
    int l15 = lane & 15, half = lane >> 4;
    #pragma unroll
    for (int et = 0; et < 2; ++et)
        #pragma unroll
        for (int s = 0; s < 4; ++s) {
            int e = wave * 32 + et * 16 + l15;
            int d0 = s * 32 + half * 8;
            const floatx4* p = reinterpret_cast<const floatx4*>(W + e * D_DIM + d0);
            floatx4 v0 = p[0], v1 = p[1];
            uintx4 u;
            u.x = pack_bf16_rne(v0.x, v0.y);
            u.y = pack_bf16_rne(v0.z, v0.w);
            u.z = pack_bf16_rne(v1.x, v1.y);
            u.w = pack_bf16_rne(v1.z, v1.w);
            bfr[et][s] = __builtin_bit_cast(bf16x8, u);
        }
}

// 6 m-tiles x 2 e-tiles of 16x16, K=128 in 4 steps of 32. A from swizzled LDS, B from regs.
// D layout: col = lane&15, row = (lane>>4)*4 + reg   [guide §3, m89-verified]
__device__ __forceinline__ void compute_tile(const short* As, const bf16x8 (&bfr)[2][4],
                                             int lane, floatx4 (&acc)[6][2]) {
    int l15 = lane & 15, half = lane >> 4;
    #pragma unroll
    for (int s = 0; s < 4; ++s) {
        int d0 = s * 32 + half * 8;
        bf16x8 a[6];
        #pragma unroll
        for (int mt = 0; mt < 6; ++mt)
            a[mt] = *reinterpret_cast<const bf16x8*>(
                        reinterpret_cast<const char*>(As) + lds_off(mt * 16 + l15, d0));
        #pragma unroll
        for (int mt = 0; mt < 6; ++mt)
            #pragma unroll
            for (int et = 0; et < 2; ++et)
                acc[mt][et] = __builtin_amdgcn_mfma_f32_16x16x32_bf16(a[mt], bfr[et][s], acc[mt][et], 0, 0, 0);
    }
}

// Pass 1: per (tile, channel): partial score = sum tanh(hs_tile @ W^T + b) . meta[c]
__global__ __launch_bounds__(256, 3) void score_kernel(
        const float* __restrict__ hs, const float* __restrict__ W,
        const float* __restrict__ bvec, const float* __restrict__ meta,
        float* __restrict__ partials) {
    __shared__ short As[M_TILE * D_DIM];
    __shared__ float red[4];
    int tile = blockIdx.x, c = blockIdx.y, tid = threadIdx.x;
    int wave = tid >> 6, lane = tid & 63;

    bf16x8 bfr[2][4];
    load_w_frags(W, wave, lane, bfr);

    const float* src = hs + (size_t)c * N_NODES * D_DIM + (size_t)tile * M_TILE * D_DIM;
    #pragma unroll
    for (int j = 0; j < 12; ++j) {              // 96*32/256 float4 per thread
        int q = j * 256 + tid;
        floatx4 v = reinterpret_cast<const floatx4*>(src)[q];
        int row = q >> 5, d0 = (q & 31) * 4;
        uintx2 w;
        w.x = pack_bf16_rne(v.x, v.y);
        w.y = pack_bf16_rne(v.z, v.w);
        *reinterpret_cast<uintx2*>(reinterpret_cast<char*>(As) + lds_off(row, d0)) = w;
    }
    __syncthreads();

    floatx4 acc[6][2];
    #pragma unroll
    for (int mt = 0; mt < 6; ++mt)
        #pragma unroll
        for (int et = 0; et < 2; ++et)
            acc[mt][et] = (floatx4){0.f, 0.f, 0.f, 0.f};
    compute_tile(As, bfr, lane, acc);

    int l15 = lane & 15;
    float p = 0.f;
    #pragma unroll
    for (int et = 0; et < 2; ++et) {
        int e = wave * 32 + et * 16 + l15;
        float be = bvec[e];
        float me = meta[c * D_DIM + e];
        #pragma unroll
        for (int mt = 0; mt < 6; ++mt)
            #pragma unroll
            for (int r = 0; r < 4; ++r)
                p += fast_tanh(acc[mt][et][r] + be) * me;
    }
    #pragma unroll
    for (int off = 32; off > 0; off >>= 1) p += __shfl_down(p, off);
    if (lane == 0) red[wave] = p;
    __syncthreads();
    if (tid == 0) partials[c * N_TILES + tile] = red[0] + red[1] + red[2] + red[3];
}

// Pass 2: deterministic reduce + softmax over 4 channels
__global__ void softmax_kernel(const float* __restrict__ partials, float* __restrict__ att_out) {
    __shared__ float red[4];
    __shared__ float totals[C_CH];
    int tid = threadIdx.x;
    int wave = tid >> 6, lane = tid & 63;
    for (int c = 0; c < C_CH; ++c) {
        float s = 0.f;
        for (int i = tid; i < N_TILES; i += 256) s += partials[c * N_TILES + i];
        #pragma unroll
        for (int off = 32; off > 0; off >>= 1) s += __shfl_down(s, off);
        if (lane == 0) red[wave] = s;
        __syncthreads();
        if (tid == 0) totals[c] = red[0] + red[1] + red[2] + red[3];
        __syncthreads();
    }
    if (tid == 0) {
        float sc[C_CH], m = -1e30f;
        #pragma unroll
        for (int c = 0; c < C_CH; ++c) {
            sc[c] = totals[c] / (float)N_NODES;
            m = fmaxf(m, sc[c]);
        }
        float sum = 0.f;
        #pragma unroll
        for (int c = 0; c < C_CH; ++c) {
            sc[c] = __builtin_amdgcn_exp2f((sc[c] - m) * 1.4426950408889634f);
            sum += sc[c];
        }
        #pragma unroll
        for (int c = 0; c < C_CH; ++c) att_out[c] = sc[c] / sum;
    }
}

// Pass 3: recompute h per channel, out = sum_c att[c]*tanh(z+b).
// Reversed tile order consumes the L3-resident tail the score pass left behind;
// nontemporal loads/stores keep this pass's single-use traffic from evicting it.
__global__ __launch_bounds__(256, 2) void out_kernel(
        const float* __restrict__ hs, const float* __restrict__ W,
        const float* __restrict__ bvec, const float* __restrict__ att,
        float* __restrict__ out) {
    __shared__ short As[M_TILE * D_DIM];
    int tile = N_TILES - 1 - blockIdx.x;            // reverse order for L3 tail reuse
    int tid = threadIdx.x, wave = tid >> 6, lane = tid & 63;
    int l15 = lane & 15, half = lane >> 4;

    bf16x8 bfr[2][4];
    load_w_frags(W, wave, lane, bfr);

    float be[2];
    #pragma unroll
    for (int et = 0; et < 2; ++et) be[et] = bvec[wave * 32 + et * 16 + l15];
    float av[C_CH];
    #pragma unroll
    for (int c = 0; c < C_CH; ++c) av[c] = att[c];

    floatx4 oacc[6][2];
    #pragma unroll
    for (int mt = 0; mt < 6; ++mt)
        #pragma unroll
        for (int et = 0; et < 2; ++et)
            oacc[mt][et] = (floatx4){0.f, 0.f, 0.f, 0.f};

    const float* base = hs + (size_t)tile * M_TILE * D_DIM;
    floatx4 R[12];
    #pragma unroll
    for (int j = 0; j < 12; ++j)
        R[j] = __builtin_nontemporal_load(reinterpret_cast<const floatx4*>(base) + j * 256 + tid);

    #pragma unroll
    for (int c = 0; c < C_CH; ++c) {
        __syncthreads();                     // prev compute done, As free
        #pragma unroll
        for (int j = 0; j < 12; ++j) {       // write staged regs (channel c) to LDS
            int q = j * 256 + tid;
            int row = q >> 5, d0 = (q & 31) * 4;
            uintx2 w;
            w.x = pack_bf16_rne(R[j].x, R[j].y);
            w.y = pack_bf16_rne(R[j].z, R[j].w);
            *reinterpret_cast<uintx2*>(reinterpret_cast<char*>(As) + lds_off(row, d0)) = w;
        }
        __syncthreads();                     // As ready
        if (c < C_CH - 1) {                  // T14: issue next channel's loads before compute
            const float* nsrc = base + (size_t)(c + 1) * N_NODES * D_DIM;
            #pragma unroll
            for (int j = 0; j < 12; ++j)
                R[j] = __builtin_nontemporal_load(reinterpret_cast<const floatx4*>(nsrc) + j * 256 + tid);
        }
        floatx4 acc[6][2];
        #pragma unroll
        for (int mt = 0; mt < 6; ++mt)
            #pragma unroll
            for (int et = 0; et < 2; ++et)
                acc[mt][et] = (floatx4){0.f, 0.f, 0.f, 0.f};
        compute_tile(As, bfr, lane, acc);
        #pragma unroll
        for (int mt = 0; mt < 6; ++mt)
            #pragma unroll
            for (int et = 0; et < 2; ++et)
                #pragma unroll
                for (int r = 0; r < 4; ++r)
                    oacc[mt][et][r] += av[c] * fast_tanh(acc[mt][et][r] + be[et]);
    }

    #pragma unroll
    for (int mt = 0; mt < 6; ++mt)
        #pragma unroll
        for (int et = 0; et < 2; ++et)
            #pragma unroll
            for (int r = 0; r < 4; ++r) {
                int rown = tile * M_TILE + mt * 16 + half * 4 + r;
                int e = wave * 32 + et * 16 + l15;
                __builtin_nontemporal_store(oacc[mt][et][r], out + (size_t)rown * D_DIM + e);
            }
}

extern "C" void kernel_launch(void* const* d_in, const int* in_sizes, int n_in,
                              void* d_out, int out_size, void* d_ws, size_t ws_size,
                              hipStream_t stream) {
    (void)in_sizes; (void)n_in; (void)out_size; (void)ws_size;
    const float* hs   = (const float*)d_in[0];
    const float* W    = (const float*)d_in[1];
    const float* bv   = (const float*)d_in[2];
    const float* meta = (const float*)d_in[3];
    float* wsf = (float*)d_ws;
    float* partials = wsf;                    // [4][3125]
    float* att      = wsf + C_CH * N_TILES;   // [4]
    float* out      = (float*)d_out;

    score_kernel<<<dim3(N_TILES, C_CH), 256, 0, stream>>>(hs, W, bv, meta, partials);
    softmax_kernel<<<1, 256, 0, stream>>>(partials, att);
    out_kernel<<<N_TILES, 256, 0, stream>>>(hs, W, bv, att, out);
}